// Round 3
// baseline (121.454 us; speedup 1.0000x reference)
//
#include <hip/hip_runtime.h>

#define HWSZ 16384      // H*W
#define Wd 128
#define Hd 128
#define Dd 48
#define Cc 32
#define Gg 8
#define Vv 5
#define DHW (Dd*HWSZ)   // 786432
#define NCHUNK 4
#define DCH (Dd/NCHUNK) // 12 depths per thread

typedef float float4a __attribute__((ext_vector_type(4), aligned(4)));

// ---------------- kernel 1: proj matrices (4 views x 3x4) ----------------
__global__ void k_proj(const float* __restrict__ am, const float* __restrict__ ainv,
                       const int* __restrict__ idx, float* __restrict__ proj) {
    int t = threadIdx.x;
    if (t >= 4) return;
    int i0 = idx[0];
    int ii = idx[t + 1];
    const float* A  = am   + ii * 16;
    const float* Mi = ainv + i0 * 16;
    for (int r = 0; r < 3; ++r)
        for (int c = 0; c < 4; ++c) {
            float s = 0.f;
            for (int k = 0; k < 4; ++k) s += A[r*4+k] * Mi[k*4+c];
            proj[t*12 + r*4 + c] = s;
        }
}

// ---------------- kernel 2: transpose (C,H,W) -> (H,W,C), LDS-tiled -------
__global__ __launch_bounds__(256) void k_transpose(const float* __restrict__ feats,
                                                   const int* __restrict__ idx,
                                                   float* __restrict__ refT,
                                                   float* __restrict__ srcT) {
    __shared__ float tile[Cc][64 + 1];
    int t = threadIdx.x;
    int slot = blockIdx.x >> 8;
    int px0  = (blockIdx.x & 255) << 6;
    int v = idx[slot];
    const float* s = feats + (size_t)v * Cc * HWSZ + px0;
    int cr = t >> 6;
    int pr = t & 63;
#pragma unroll
    for (int k = 0; k < 8; ++k) {
        int c = cr + k * 4;
        tile[c][pr] = s[(size_t)c * HWSZ + pr];
    }
    __syncthreads();
    float* dbase = (slot == 0) ? (refT + ((size_t)px0 << 5))
                               : (srcT + (size_t)(slot - 1) * Cc * HWSZ + ((size_t)px0 << 5));
    int cw = t & 31;
    int pw = t >> 5;
#pragma unroll
    for (int k = 0; k < 8; ++k) {
        int p = pw + k * 8;
        dbase[((size_t)p << 5) + cw] = tile[cw][p];
    }
}

// ---------------- kernel 3 (TR path): warp + group correlation ------------
// 8 lanes per pixel (one per group). Setup dedup: lane computes bilinear
// setup for view (g&3) ONLY — all 4 views' setups run in one SIMD pass —
// then weights/offsets are shared across the pixel-octet via __shfl
// (ds_bpermute: LDS pipe, VALU stays free). Thread loops 12 depths so the
// depth-independent rotation terms are hoisted.
__global__ __launch_bounds__(256) void k_volume8(const float* __restrict__ srcT,
                                                 const float* __restrict__ refT,
                                                 const float* __restrict__ dvals,
                                                 const float* __restrict__ proj,
                                                 float* __restrict__ volume) {
    int t = threadIdx.x;
    int g = t & 7;
    int vs = g & 3;                 // view this lane does setup for
    int lanebase = t & 56;          // octet base lane within wave

    int tid = blockIdx.x * 256 + t;
    int pix = (tid >> 3) & (HWSZ - 1);
    int chunk = tid >> 17;          // 0..NCHUNK-1
    int w = pix & (Wd - 1);
    int h = pix >> 7;
    float fx = (float)w, fy = (float)h;

    const float4* pj = (const float4*)(proj + vs * 12);
    float4 pa = pj[0], pb = pj[1], pc = pj[2];
    float rx = pa.x * fx + pa.y * fy + pa.z;
    float ry = pb.x * fx + pb.y * fy + pb.z;
    float rz = pc.x * fx + pc.y * fy + pc.z;
    float tx = pa.w, ty = pb.w, tz = pc.w;

    float4 r4 = *(const float4*)(refT + ((size_t)pix << 5) + (g << 2));
    int g16 = g << 4;               // byte offset of group's 4 channels

    const float* dv = dvals + (size_t)chunk * DCH * HWSZ + pix;
    float* vo = volume + (size_t)g * DHW + (size_t)chunk * DCH * HWSZ + pix;

#pragma unroll 2
    for (int dd = 0; dd < DCH; ++dd) {
        float dep = dv[(size_t)dd * HWSZ];
        float sx = rx * dep + tx;
        float sy = ry * dep + ty;
        float sz = rz * dep + tz;
        sz = (fabsf(sz) < 1e-6f) ? 1e-6f : sz;
        float rzi = 1.0f / sz;
        float gx = sx * rzi, gy = sy * rzi;

        float x0f = floorf(gx), y0f = floorf(gy);
        float wx1 = gx - x0f, wx0 = 1.f - wx1;
        float wy1 = gy - y0f, wy0 = 1.f - wy1;
        float x1f = x0f + 1.f, y1f = y0f + 1.f;
        float x0c = fminf(fmaxf(x0f, 0.f), (float)(Wd-1));
        float x1c = fminf(fmaxf(x1f, 0.f), (float)(Wd-1));
        float y0c = fminf(fmaxf(y0f, 0.f), (float)(Hd-1));
        float y1c = fminf(fmaxf(y1f, 0.f), (float)(Hd-1));
        float wx0z = (x0c == x0f) ? wx0 : 0.f;   // in-bounds <=> clamp is identity
        float wx1z = (x1c == x1f) ? wx1 : 0.f;
        float wy0z = (y0c == y0f) ? wy0 : 0.f;
        float wy1z = (y1c == y1f) ? wy1 : 0.f;
        float w00 = wx0z * wy0z, w10 = wx1z * wy0z;
        float w01 = wx0z * wy1z, w11 = wx1z * wy1z;
        int x0 = (int)x0c, x1 = (int)x1c, y0 = (int)y0c, y1 = (int)y1c;
        int bo00 = ((y0 << 7) + x0) << 7;        // pixel byte offset (x128B)
        int bo10 = ((y0 << 7) + x1) << 7;
        int bo01 = ((y1 << 7) + x0) << 7;
        int bo11 = ((y1 << 7) + x1) << 7;

        float ax = 0.f, ay = 0.f, az = 0.f, aw = 0.f;
#pragma unroll
        for (int v = 0; v < 4; ++v) {
            int src = lanebase + v;
            float W00 = __shfl(w00, src);
            float W10 = __shfl(w10, src);
            float W01 = __shfl(w01, src);
            float W11 = __shfl(w11, src);
            int B00 = __shfl(bo00, src);
            int B10 = __shfl(bo10, src);
            int B01 = __shfl(bo01, src);
            int B11 = __shfl(bo11, src);
            const char* base = (const char*)srcT + (size_t)v * ((size_t)Cc * HWSZ * 4);
            float4 t00 = *(const float4*)(base + (B00 + g16));
            float4 t10 = *(const float4*)(base + (B10 + g16));
            float4 t01 = *(const float4*)(base + (B01 + g16));
            float4 t11 = *(const float4*)(base + (B11 + g16));
            ax += t00.x*W00 + t10.x*W10 + t01.x*W01 + t11.x*W11;
            ay += t00.y*W00 + t10.y*W10 + t01.y*W01 + t11.y*W11;
            az += t00.z*W00 + t10.z*W10 + t01.z*W01 + t11.z*W11;
            aw += t00.w*W00 + t10.w*W10 + t01.w*W01 + t11.w*W11;
        }
        float s = r4.x*ax + r4.y*ay + r4.z*az + r4.w*aw;
        vo[(size_t)dd * HWSZ] = s * (1.f / 16.f);
    }
}

// ---------------- kernel 3 (fallback, no workspace): original layout ------
__global__ __launch_bounds__(256) void k_volume_fb(const float* __restrict__ featsrc,
                                                   const int* __restrict__ idx,
                                                   const float* __restrict__ dvals,
                                                   const float* __restrict__ proj,
                                                   float* __restrict__ volume) {
    __shared__ float P[48];
    __shared__ int sidx[5];
    int t = threadIdx.x;
    if (t < 48) P[t] = proj[t];
    if (t < 5)  sidx[t] = idx[t];
    __syncthreads();

    int tid = blockIdx.x * 256 + t;
    int w = tid & (Wd - 1);
    int h = (tid >> 7) & (Hd - 1);
    int pix = tid & (HWSZ - 1);
    float fx = (float)w, fy = (float)h;
    float dep = dvals[tid];

    float acc[Cc];
#pragma unroll
    for (int c = 0; c < Cc; ++c) acc[c] = 0.f;

#pragma unroll 1
    for (int v = 0; v < 4; ++v) {
        const float* p = &P[v * 12];
        float sx = (p[0]*fx + p[1]*fy + p[2])  * dep + p[3];
        float sy = (p[4]*fx + p[5]*fy + p[6])  * dep + p[7];
        float sz = (p[8]*fx + p[9]*fy + p[10]) * dep + p[11];
        sz = (fabsf(sz) < 1e-6f) ? 1e-6f : sz;
        float gx = sx / sz, gy = sy / sz;

        float x0f = floorf(gx), y0f = floorf(gy);
        float wx1 = gx - x0f, wx0 = 1.f - wx1;
        float wy1 = gy - y0f, wy0 = 1.f - wy1;
        float x1f = x0f + 1.f, y1f = y0f + 1.f;
        bool xi0 = (x0f >= 0.f) && (x0f <= (float)(Wd-1));
        bool xi1 = (x1f >= 0.f) && (x1f <= (float)(Wd-1));
        bool yi0 = (y0f >= 0.f) && (y0f <= (float)(Hd-1));
        bool yi1 = (y1f >= 0.f) && (y1f <= (float)(Hd-1));
        float w00 = wx0*wy0 * ((xi0 && yi0) ? 1.f : 0.f);
        float w10 = wx1*wy0 * ((xi1 && yi0) ? 1.f : 0.f);
        float w01 = wx0*wy1 * ((xi0 && yi1) ? 1.f : 0.f);
        float w11 = wx1*wy1 * ((xi1 && yi1) ? 1.f : 0.f);
        int x0 = (int)fminf(fmaxf(x0f, 0.f), (float)(Wd-1));
        int x1 = (int)fminf(fmaxf(x1f, 0.f), (float)(Wd-1));
        int y0 = (int)fminf(fmaxf(y0f, 0.f), (float)(Hd-1));
        int y1 = (int)fminf(fmaxf(y1f, 0.f), (float)(Hd-1));

        int vv = sidx[v + 1];
        const float* base = featsrc + (size_t)vv * Cc * HWSZ;
        int o00 = y0*Wd + x0, o10 = y0*Wd + x1, o01 = y1*Wd + x0, o11 = y1*Wd + x1;
#pragma unroll
        for (int c = 0; c < Cc; ++c) {
            const float* bc = base + (size_t)c * HWSZ;
            acc[c] += bc[o00]*w00 + bc[o10]*w10 + bc[o01]*w01 + bc[o11]*w11;
        }
    }

    float ref[Cc];
    int v0 = sidx[0];
    const float* rb = featsrc + (size_t)v0 * Cc * HWSZ + pix;
#pragma unroll
    for (int c = 0; c < Cc; ++c) ref[c] = rb[(size_t)c * HWSZ];
#pragma unroll
    for (int g = 0; g < Gg; ++g) {
        float s = ref[g*4+0]*acc[g*4+0] + ref[g*4+1]*acc[g*4+1]
                + ref[g*4+2]*acc[g*4+2] + ref[g*4+3]*acc[g*4+3];
        volume[(size_t)g * DHW + tid] = s * (1.f / 16.f);
    }
}

// ---------------- kernel 4: 3D conv (G->1, 3x3x3, SAME), Wtile=4 ----------
__global__ __launch_bounds__(256) void k_conv(const float* __restrict__ volume,
                                              const float* __restrict__ cw,
                                              const float* __restrict__ cb,
                                              float* __restrict__ dp) {
    __shared__ float Wk[216];
    __shared__ float bias;
    int t = threadIdx.x;
    if (t < 216) Wk[t] = cw[t];
    if (t == 0) bias = cb[0];
    __syncthreads();

    int T  = blockIdx.x * 256 + t;
    int wg = T & 31;
    int w0 = wg << 2;
    int h  = (T >> 5) & 127;
    int d  = T >> 12;
    bool left  = (w0 == 0);
    bool right = (w0 == 124);
    int c0 = left  ? 0   : w0 - 1;
    int c1 = right ? 124 : w0 + 1;

    float acc0 = 0.f, acc1 = 0.f, acc2 = 0.f, acc3 = 0.f;

#pragma unroll 1
    for (int g = 0; g < Gg; ++g) {
        float wt[27];
#pragma unroll
        for (int j = 0; j < 27; ++j) wt[j] = Wk[g * 27 + j];
        const float* vg = volume + (size_t)g * DHW;
#pragma unroll
        for (int pz = 0; pz < 3; ++pz) {
            int dd = d - 1 + pz;
            if (dd < 0 || dd >= Dd) continue;
            const float* vp = vg + (size_t)dd * HWSZ;
#pragma unroll
            for (int dy = 0; dy < 3; ++dy) {
                int hh = h - 1 + dy;
                if (hh < 0 || hh >= Hd) continue;
                const float* vr = vp + hh * Wd;
                float4a L0 = *(const float4a*)(vr + c0);
                float4a L1 = *(const float4a*)(vr + c1);
                float n0 = left  ? 0.f  : L0.x;
                float n1 = left  ? L0.x : L0.y;
                float n2 = left  ? L0.y : L0.z;
                float n3 = left  ? L0.z : L0.w;
                float n4 = right ? L1.w : L1.z;
                float n5 = right ? 0.f  : L1.w;
                float wa = wt[pz*9 + dy*3 + 0];
                float wb = wt[pz*9 + dy*3 + 1];
                float wc = wt[pz*9 + dy*3 + 2];
                acc0 += n0*wa + n1*wb + n2*wc;
                acc1 += n1*wa + n2*wb + n3*wc;
                acc2 += n2*wa + n3*wb + n4*wc;
                acc3 += n3*wa + n4*wb + n5*wc;
            }
        }
    }
    size_t o = (size_t)d * HWSZ + (size_t)h * Wd + w0;
    dp[o + 0] = acc0 + bias;
    dp[o + 1] = acc1 + bias;
    dp[o + 2] = acc2 + bias;
    dp[o + 3] = acc3 + bias;
}

// ---------------- kernel 5: softmax over D + expected depth ---------------
__global__ __launch_bounds__(256) void k_depth(const float* __restrict__ dp,
                                               const float* __restrict__ dvals,
                                               float* __restrict__ out) {
    int pix = blockIdx.x * 256 + threadIdx.x;
    float p[Dd];
#pragma unroll
    for (int d = 0; d < Dd; ++d) p[d] = dp[(size_t)d * HWSZ + pix];
    float m = p[0];
#pragma unroll
    for (int d = 1; d < Dd; ++d) m = fmaxf(m, p[d]);
    float se = 0.f, acc = 0.f;
#pragma unroll
    for (int d = 0; d < Dd; ++d) {
        float e = __expf(p[d] - m);
        se += e;
        acc += e * dvals[(size_t)d * HWSZ + pix];
    }
    out[pix] = acc / se;
}

extern "C" void kernel_launch(void* const* d_in, const int* in_sizes, int n_in,
                              void* d_out, int out_size, void* d_ws, size_t ws_size,
                              hipStream_t stream) {
    const float* feats = (const float*)d_in[0];
    const float* am    = (const float*)d_in[1];
    const float* ainv  = (const float*)d_in[2];
    const float* dvals = (const float*)d_in[3];
    const float* cw    = (const float*)d_in[4];
    const float* cb    = (const float*)d_in[5];
    const int*   idx   = (const int*)d_in[6];

    float* out    = (float*)d_out;
    float* volume = out;                         // G*D*H*W
    float* depth  = out + (size_t)Gg * DHW;      // H*W

    float* ws   = (float*)d_ws;
    float* proj = ws;                            // 48 floats (pad to 256)
    float* dp   = ws + 256;                      // DHW floats
    float* refT = ws + 256 + DHW;                // Cc*HWSZ floats
    float* srcT = refT + (size_t)Cc * HWSZ;      // 4*Cc*HWSZ floats
    size_t need = (256 + (size_t)DHW + (size_t)Cc * HWSZ * 5) * sizeof(float);
    bool tr = ws_size >= need;

    k_proj<<<dim3(1), dim3(64), 0, stream>>>(am, ainv, idx, proj);
    if (tr) {
        k_transpose<<<dim3((Vv * HWSZ) / 64), dim3(256), 0, stream>>>(feats, idx, refT, srcT);
        k_volume8<<<dim3((HWSZ * Gg * NCHUNK) / 256), dim3(256), 0, stream>>>(srcT, refT, dvals, proj, volume);
    } else {
        k_volume_fb<<<dim3(DHW / 256), dim3(256), 0, stream>>>(feats, idx, dvals, proj, volume);
    }
    k_conv<<<dim3(DHW / 1024), dim3(256), 0, stream>>>(volume, cw, cb, dp);
    k_depth<<<dim3(HWSZ / 256), dim3(256), 0, stream>>>(dp, dvals, depth);
}

// Round 4
// 102.748 us; speedup vs baseline: 1.1820x; 1.1820x over previous
//
#include <hip/hip_runtime.h>

#define HWSZ 16384      // H*W
#define Wd 128
#define Hd 128
#define Dd 48
#define Cc 32
#define Gg 8
#define Vv 5
#define DHW (Dd*HWSZ)   // 786432
#define NCHUNK 8
#define DCH (Dd/NCHUNK) // 6 depths per thread

typedef float float4a __attribute__((ext_vector_type(4), aligned(4)));

// ---------------- kernel 1: proj matrices (4 views x 3x4) ----------------
__global__ void k_proj(const float* __restrict__ am, const float* __restrict__ ainv,
                       const int* __restrict__ idx, float* __restrict__ proj) {
    int t = threadIdx.x;
    if (t >= 4) return;
    int i0 = idx[0];
    int ii = idx[t + 1];
    const float* A  = am   + ii * 16;
    const float* Mi = ainv + i0 * 16;
    for (int r = 0; r < 3; ++r)
        for (int c = 0; c < 4; ++c) {
            float s = 0.f;
            for (int k = 0; k < 4; ++k) s += A[r*4+k] * Mi[k*4+c];
            proj[t*12 + r*4 + c] = s;
        }
}

// ---------------- kernel 2: transpose (C,H,W) -> (H,W,C), LDS-tiled -------
__global__ __launch_bounds__(256) void k_transpose(const float* __restrict__ feats,
                                                   const int* __restrict__ idx,
                                                   float* __restrict__ refT,
                                                   float* __restrict__ srcT) {
    __shared__ float tile[Cc][64 + 1];
    int t = threadIdx.x;
    int slot = blockIdx.x >> 8;
    int px0  = (blockIdx.x & 255) << 6;
    int v = idx[slot];
    const float* s = feats + (size_t)v * Cc * HWSZ + px0;
    int cr = t >> 6;
    int pr = t & 63;
#pragma unroll
    for (int k = 0; k < 8; ++k) {
        int c = cr + k * 4;
        tile[c][pr] = s[(size_t)c * HWSZ + pr];
    }
    __syncthreads();
    float* dbase = (slot == 0) ? (refT + ((size_t)px0 << 5))
                               : (srcT + (size_t)(slot - 1) * Cc * HWSZ + ((size_t)px0 << 5));
    int cw = t & 31;
    int pw = t >> 5;
#pragma unroll
    for (int k = 0; k < 8; ++k) {
        int p = pw + k * 8;
        dbase[((size_t)p << 5) + cw] = tile[cw][p];
    }
}

// ---------------- kernel 3 (TR path): warp + group correlation ------------
// 8 lanes per pixel (one per group); lane-private setup (no cross-lane ops —
// R2's shfl dedup serialized the pipeline and regressed). VALU cuts vs R1:
// depth-invariant rotation hoisted across DCH depths, single v_rcp_f32
// instead of two IEEE divides, clamp-identity bounds test.
__global__ __launch_bounds__(256) void k_volume8(const float* __restrict__ srcT,
                                                 const float* __restrict__ refT,
                                                 const float* __restrict__ dvals,
                                                 const float* __restrict__ proj,
                                                 float* __restrict__ volume) {
    int t = threadIdx.x;
    int g = t & 7;
    int tid = blockIdx.x * 256 + t;
    int pix = (tid >> 3) & (HWSZ - 1);
    int chunk = tid >> 17;              // 0..NCHUNK-1  (2^17 = HWSZ*8)
    int w = pix & (Wd - 1);
    int h = pix >> 7;
    float fx = (float)w, fy = (float)h;

    // depth-invariant rotation terms, all 4 views (uniform proj -> scalar loads)
    float rx[4], ry[4], rz[4], tx[4], ty[4], tz[4];
#pragma unroll
    for (int v = 0; v < 4; ++v) {
        const float* p = proj + v * 12;
        rx[v] = p[0]*fx + p[1]*fy + p[2];   tx[v] = p[3];
        ry[v] = p[4]*fx + p[5]*fy + p[6];   ty[v] = p[7];
        rz[v] = p[8]*fx + p[9]*fy + p[10];  tz[v] = p[11];
    }

    float4 r4 = *(const float4*)(refT + ((size_t)pix << 5) + (g << 2));
    const char* sbase = (const char*)srcT + (g << 4);   // group channel offset

    const float* dv = dvals + (size_t)chunk * DCH * HWSZ + pix;
    float* vo = volume + (size_t)g * DHW + (size_t)chunk * DCH * HWSZ + pix;

#pragma unroll 2
    for (int dd = 0; dd < DCH; ++dd) {
        float dep = dv[(size_t)dd * HWSZ];
        float ax = 0.f, ay = 0.f, az = 0.f, aw = 0.f;
#pragma unroll
        for (int v = 0; v < 4; ++v) {
            float sx = rx[v] * dep + tx[v];
            float sy = ry[v] * dep + ty[v];
            float sz = rz[v] * dep + tz[v];
            sz = (fabsf(sz) < 1e-6f) ? 1e-6f : sz;
            float rzi = __builtin_amdgcn_rcpf(sz);
            float gx = sx * rzi, gy = sy * rzi;

            float x0f = floorf(gx), y0f = floorf(gy);
            float wx1 = gx - x0f, wx0 = 1.f - wx1;
            float wy1 = gy - y0f, wy0 = 1.f - wy1;
            float x1f = x0f + 1.f, y1f = y0f + 1.f;
            float x0c = fminf(fmaxf(x0f, 0.f), (float)(Wd-1));
            float x1c = fminf(fmaxf(x1f, 0.f), (float)(Wd-1));
            float y0c = fminf(fmaxf(y0f, 0.f), (float)(Hd-1));
            float y1c = fminf(fmaxf(y1f, 0.f), (float)(Hd-1));
            float wx0z = (x0c == x0f) ? wx0 : 0.f;   // in-bounds <=> clamp identity
            float wx1z = (x1c == x1f) ? wx1 : 0.f;
            float wy0z = (y0c == y0f) ? wy0 : 0.f;
            float wy1z = (y1c == y1f) ? wy1 : 0.f;
            float w00 = wx0z * wy0z, w10 = wx1z * wy0z;
            float w01 = wx0z * wy1z, w11 = wx1z * wy1z;
            int x0 = (int)x0c, x1 = (int)x1c, y0 = (int)y0c, y1 = (int)y1c;
            int r0 = y0 << 14, r1 = y1 << 14;        // row byte offsets
            int c0 = x0 << 7,  c1 = x1 << 7;         // col byte offsets

            const char* base = sbase + (size_t)v * ((size_t)Cc * HWSZ * 4);
            float4 t00 = *(const float4*)(base + (r0 + c0));
            float4 t10 = *(const float4*)(base + (r0 + c1));
            float4 t01 = *(const float4*)(base + (r1 + c0));
            float4 t11 = *(const float4*)(base + (r1 + c1));
            ax += t00.x*w00 + t10.x*w10 + t01.x*w01 + t11.x*w11;
            ay += t00.y*w00 + t10.y*w10 + t01.y*w01 + t11.y*w11;
            az += t00.z*w00 + t10.z*w10 + t01.z*w01 + t11.z*w11;
            aw += t00.w*w00 + t10.w*w10 + t01.w*w01 + t11.w*w11;
        }
        float s = r4.x*ax + r4.y*ay + r4.z*az + r4.w*aw;
        vo[(size_t)dd * HWSZ] = s * (1.f / 16.f);   // /(C/G)=4 then /(V-1)=4
    }
}

// ---------------- kernel 3 (fallback, no workspace): original layout ------
__global__ __launch_bounds__(256) void k_volume_fb(const float* __restrict__ featsrc,
                                                   const int* __restrict__ idx,
                                                   const float* __restrict__ dvals,
                                                   const float* __restrict__ proj,
                                                   float* __restrict__ volume) {
    __shared__ float P[48];
    __shared__ int sidx[5];
    int t = threadIdx.x;
    if (t < 48) P[t] = proj[t];
    if (t < 5)  sidx[t] = idx[t];
    __syncthreads();

    int tid = blockIdx.x * 256 + t;
    int w = tid & (Wd - 1);
    int h = (tid >> 7) & (Hd - 1);
    int pix = tid & (HWSZ - 1);
    float fx = (float)w, fy = (float)h;
    float dep = dvals[tid];

    float acc[Cc];
#pragma unroll
    for (int c = 0; c < Cc; ++c) acc[c] = 0.f;

#pragma unroll 1
    for (int v = 0; v < 4; ++v) {
        const float* p = &P[v * 12];
        float sx = (p[0]*fx + p[1]*fy + p[2])  * dep + p[3];
        float sy = (p[4]*fx + p[5]*fy + p[6])  * dep + p[7];
        float sz = (p[8]*fx + p[9]*fy + p[10]) * dep + p[11];
        sz = (fabsf(sz) < 1e-6f) ? 1e-6f : sz;
        float gx = sx / sz, gy = sy / sz;

        float x0f = floorf(gx), y0f = floorf(gy);
        float wx1 = gx - x0f, wx0 = 1.f - wx1;
        float wy1 = gy - y0f, wy0 = 1.f - wy1;
        float x1f = x0f + 1.f, y1f = y0f + 1.f;
        bool xi0 = (x0f >= 0.f) && (x0f <= (float)(Wd-1));
        bool xi1 = (x1f >= 0.f) && (x1f <= (float)(Wd-1));
        bool yi0 = (y0f >= 0.f) && (y0f <= (float)(Hd-1));
        bool yi1 = (y1f >= 0.f) && (y1f <= (float)(Hd-1));
        float w00 = wx0*wy0 * ((xi0 && yi0) ? 1.f : 0.f);
        float w10 = wx1*wy0 * ((xi1 && yi0) ? 1.f : 0.f);
        float w01 = wx0*wy1 * ((xi0 && yi1) ? 1.f : 0.f);
        float w11 = wx1*wy1 * ((xi1 && yi1) ? 1.f : 0.f);
        int x0 = (int)fminf(fmaxf(x0f, 0.f), (float)(Wd-1));
        int x1 = (int)fminf(fmaxf(x1f, 0.f), (float)(Wd-1));
        int y0 = (int)fminf(fmaxf(y0f, 0.f), (float)(Hd-1));
        int y1 = (int)fminf(fmaxf(y1f, 0.f), (float)(Hd-1));

        int vv = sidx[v + 1];
        const float* base = featsrc + (size_t)vv * Cc * HWSZ;
        int o00 = y0*Wd + x0, o10 = y0*Wd + x1, o01 = y1*Wd + x0, o11 = y1*Wd + x1;
#pragma unroll
        for (int c = 0; c < Cc; ++c) {
            const float* bc = base + (size_t)c * HWSZ;
            acc[c] += bc[o00]*w00 + bc[o10]*w10 + bc[o01]*w01 + bc[o11]*w11;
        }
    }

    float ref[Cc];
    int v0 = sidx[0];
    const float* rb = featsrc + (size_t)v0 * Cc * HWSZ + pix;
#pragma unroll
    for (int c = 0; c < Cc; ++c) ref[c] = rb[(size_t)c * HWSZ];
#pragma unroll
    for (int g = 0; g < Gg; ++g) {
        float s = ref[g*4+0]*acc[g*4+0] + ref[g*4+1]*acc[g*4+1]
                + ref[g*4+2]*acc[g*4+2] + ref[g*4+3]*acc[g*4+3];
        volume[(size_t)g * DHW + tid] = s * (1.f / 16.f);
    }
}

// ---------------- kernel 4: 3D conv (G->1, 3x3x3, SAME), Wtile=4 ----------
__global__ __launch_bounds__(256) void k_conv(const float* __restrict__ volume,
                                              const float* __restrict__ cw,
                                              const float* __restrict__ cb,
                                              float* __restrict__ dp) {
    __shared__ float Wk[216];
    __shared__ float bias;
    int t = threadIdx.x;
    if (t < 216) Wk[t] = cw[t];
    if (t == 0) bias = cb[0];
    __syncthreads();

    int T  = blockIdx.x * 256 + t;
    int wg = T & 31;
    int w0 = wg << 2;
    int h  = (T >> 5) & 127;
    int d  = T >> 12;
    bool left  = (w0 == 0);
    bool right = (w0 == 124);
    int c0 = left  ? 0   : w0 - 1;
    int c1 = right ? 124 : w0 + 1;

    float acc0 = 0.f, acc1 = 0.f, acc2 = 0.f, acc3 = 0.f;

#pragma unroll 1
    for (int g = 0; g < Gg; ++g) {
        float wt[27];
#pragma unroll
        for (int j = 0; j < 27; ++j) wt[j] = Wk[g * 27 + j];
        const float* vg = volume + (size_t)g * DHW;
#pragma unroll
        for (int pz = 0; pz < 3; ++pz) {
            int dd = d - 1 + pz;
            if (dd < 0 || dd >= Dd) continue;
            const float* vp = vg + (size_t)dd * HWSZ;
#pragma unroll
            for (int dy = 0; dy < 3; ++dy) {
                int hh = h - 1 + dy;
                if (hh < 0 || hh >= Hd) continue;
                const float* vr = vp + hh * Wd;
                float4a L0 = *(const float4a*)(vr + c0);
                float4a L1 = *(const float4a*)(vr + c1);
                float n0 = left  ? 0.f  : L0.x;
                float n1 = left  ? L0.x : L0.y;
                float n2 = left  ? L0.y : L0.z;
                float n3 = left  ? L0.z : L0.w;
                float n4 = right ? L1.w : L1.z;
                float n5 = right ? 0.f  : L1.w;
                float wa = wt[pz*9 + dy*3 + 0];
                float wb = wt[pz*9 + dy*3 + 1];
                float wc = wt[pz*9 + dy*3 + 2];
                acc0 += n0*wa + n1*wb + n2*wc;
                acc1 += n1*wa + n2*wb + n3*wc;
                acc2 += n2*wa + n3*wb + n4*wc;
                acc3 += n3*wa + n4*wb + n5*wc;
            }
        }
    }
    size_t o = (size_t)d * HWSZ + (size_t)h * Wd + w0;
    dp[o + 0] = acc0 + bias;
    dp[o + 1] = acc1 + bias;
    dp[o + 2] = acc2 + bias;
    dp[o + 3] = acc3 + bias;
}

// ---------------- kernel 5: softmax over D + expected depth ---------------
__global__ __launch_bounds__(256) void k_depth(const float* __restrict__ dp,
                                               const float* __restrict__ dvals,
                                               float* __restrict__ out) {
    int pix = blockIdx.x * 256 + threadIdx.x;
    float p[Dd];
#pragma unroll
    for (int d = 0; d < Dd; ++d) p[d] = dp[(size_t)d * HWSZ + pix];
    float m = p[0];
#pragma unroll
    for (int d = 1; d < Dd; ++d) m = fmaxf(m, p[d]);
    float se = 0.f, acc = 0.f;
#pragma unroll
    for (int d = 0; d < Dd; ++d) {
        float e = __expf(p[d] - m);
        se += e;
        acc += e * dvals[(size_t)d * HWSZ + pix];
    }
    out[pix] = acc / se;
}

extern "C" void kernel_launch(void* const* d_in, const int* in_sizes, int n_in,
                              void* d_out, int out_size, void* d_ws, size_t ws_size,
                              hipStream_t stream) {
    const float* feats = (const float*)d_in[0];
    const float* am    = (const float*)d_in[1];
    const float* ainv  = (const float*)d_in[2];
    const float* dvals = (const float*)d_in[3];
    const float* cw    = (const float*)d_in[4];
    const float* cb    = (const float*)d_in[5];
    const int*   idx   = (const int*)d_in[6];

    float* out    = (float*)d_out;
    float* volume = out;                         // G*D*H*W
    float* depth  = out + (size_t)Gg * DHW;      // H*W

    float* ws   = (float*)d_ws;
    float* proj = ws;                            // 48 floats (pad to 256)
    float* dp   = ws + 256;                      // DHW floats
    float* refT = ws + 256 + DHW;                // Cc*HWSZ floats
    float* srcT = refT + (size_t)Cc * HWSZ;      // 4*Cc*HWSZ floats
    size_t need = (256 + (size_t)DHW + (size_t)Cc * HWSZ * 5) * sizeof(float);
    bool tr = ws_size >= need;

    k_proj<<<dim3(1), dim3(64), 0, stream>>>(am, ainv, idx, proj);
    if (tr) {
        k_transpose<<<dim3((Vv * HWSZ) / 64), dim3(256), 0, stream>>>(feats, idx, refT, srcT);
        k_volume8<<<dim3((HWSZ * Gg * NCHUNK) / 256), dim3(256), 0, stream>>>(srcT, refT, dvals, proj, volume);
    } else {
        k_volume_fb<<<dim3(DHW / 256), dim3(256), 0, stream>>>(feats, idx, dvals, proj, volume);
    }
    k_conv<<<dim3(DHW / 1024), dim3(256), 0, stream>>>(volume, cw, cb, dp);
    k_depth<<<dim3(HWSZ / 256), dim3(256), 0, stream>>>(dp, dvals, depth);
}

// Round 5
// 96.633 us; speedup vs baseline: 1.2569x; 1.0633x over previous
//
#include <hip/hip_runtime.h>

#define HWSZ 16384      // H*W
#define Wd 128
#define Hd 128
#define Dd 48
#define Cc 32
#define Gg 8
#define Vv 5
#define DHW (Dd*HWSZ)   // 786432
#define NCHUNK 8
#define DCH (Dd/NCHUNK) // 6 depths per thread

typedef float float4a __attribute__((ext_vector_type(4), aligned(4)));
typedef float vf2 __attribute__((ext_vector_type(2)));
typedef float vf4 __attribute__((ext_vector_type(4)));

// ---------------- kernel 1: proj matrices (4 views x 3x4) ----------------
__global__ void k_proj(const float* __restrict__ am, const float* __restrict__ ainv,
                       const int* __restrict__ idx, float* __restrict__ proj) {
    int t = threadIdx.x;
    if (t >= 4) return;
    int i0 = idx[0];
    int ii = idx[t + 1];
    const float* A  = am   + ii * 16;
    const float* Mi = ainv + i0 * 16;
    for (int r = 0; r < 3; ++r)
        for (int c = 0; c < 4; ++c) {
            float s = 0.f;
            for (int k = 0; k < 4; ++k) s += A[r*4+k] * Mi[k*4+c];
            proj[t*12 + r*4 + c] = s;
        }
}

// ---------------- kernel 2: transpose (C,H,W) -> (H,W,C), LDS-tiled -------
__global__ __launch_bounds__(256) void k_transpose(const float* __restrict__ feats,
                                                   const int* __restrict__ idx,
                                                   float* __restrict__ refT,
                                                   float* __restrict__ srcT) {
    __shared__ float tile[Cc][64 + 1];
    int t = threadIdx.x;
    int slot = blockIdx.x >> 8;
    int px0  = (blockIdx.x & 255) << 6;
    int v = idx[slot];
    const float* s = feats + (size_t)v * Cc * HWSZ + px0;
    int cr = t >> 6;
    int pr = t & 63;
#pragma unroll
    for (int k = 0; k < 8; ++k) {
        int c = cr + k * 4;
        tile[c][pr] = s[(size_t)c * HWSZ + pr];
    }
    __syncthreads();
    float* dbase = (slot == 0) ? (refT + ((size_t)px0 << 5))
                               : (srcT + (size_t)(slot - 1) * Cc * HWSZ + ((size_t)px0 << 5));
    int cw = t & 31;
    int pw = t >> 5;
#pragma unroll
    for (int k = 0; k < 8; ++k) {
        int p = pw + k * 8;
        dbase[((size_t)p << 5) + cw] = tile[cw][p];
    }
}

// ---------------- kernel 3 (TR path): warp + group correlation ------------
// 8 lanes per pixel (one per group); lane-private setup. R4 micro-opts:
// packed f32 math (v_pk_fma_f32), wave-uniform per-view base + 32-bit
// zext voffset (SGPR-base global_load form), fmed3 clamps, uniform s_load
// of the (broadcast) depth value.
__global__ __launch_bounds__(256) void k_volume8(const float* __restrict__ srcT,
                                                 const float* __restrict__ refT,
                                                 const float* __restrict__ dvals,
                                                 const float* __restrict__ proj,
                                                 float* __restrict__ volume) {
    int t = threadIdx.x;
    int g = t & 7;
    int tid = blockIdx.x * 256 + t;
    int pix = (tid >> 3) & (HWSZ - 1);
    int chunk = tid >> 17;              // 0..NCHUNK-1  (2^17 = HWSZ*8)
    int w = pix & (Wd - 1);
    int h = pix >> 7;
    float fx = (float)w, fy = (float)h;

    // depth-invariant rotation terms, all 4 views (uniform proj -> scalar loads)
    vf2 rxy[4], txy[4];
    float rz_[4], tz_[4];
#pragma unroll
    for (int v = 0; v < 4; ++v) {
        const float* p = proj + v * 12;
        rxy[v] = (vf2){p[0]*fx + p[1]*fy + p[2], p[4]*fx + p[5]*fy + p[6]};
        txy[v] = (vf2){p[3], p[7]};
        rz_[v] = p[8]*fx + p[9]*fy + p[10];
        tz_[v] = p[11];
    }

    vf4 r4 = *(const vf4*)(refT + ((size_t)pix << 5) + (g << 2));
    int g16 = g << 4;                   // group byte offset inside a pixel line

    float* vo = volume + (size_t)g * DHW + (size_t)chunk * DCH * HWSZ + pix;

#pragma unroll 2
    for (int dd = 0; dd < DCH; ++dd) {
        // depth_values is a broadcast ramp: plane value is uniform -> s_load
        float dep = dvals[(size_t)(chunk * DCH + dd) * HWSZ];
        vf2 depv = (vf2){dep, dep};

        vf4 a4 = (vf4){0.f, 0.f, 0.f, 0.f};
#pragma unroll
        for (int v = 0; v < 4; ++v) {
            vf2 sxy = rxy[v] * depv + txy[v];
            float sz = rz_[v] * dep + tz_[v];
            sz = (fabsf(sz) < 1e-6f) ? 1e-6f : sz;
            float rzi = __builtin_amdgcn_rcpf(sz);
            vf2 gxy = sxy * (vf2){rzi, rzi};

            vf2 fl0 = (vf2){floorf(gxy.x), floorf(gxy.y)};
            vf2 w1 = gxy - fl0;                 // wx1, wy1
            vf2 w0 = (vf2){1.f, 1.f} - w1;      // wx0, wy0
            vf2 fl1 = fl0 + (vf2){1.f, 1.f};
            float x0c = __builtin_amdgcn_fmed3f(fl0.x, 0.f, (float)(Wd-1));
            float x1c = __builtin_amdgcn_fmed3f(fl1.x, 0.f, (float)(Wd-1));
            float y0c = __builtin_amdgcn_fmed3f(fl0.y, 0.f, (float)(Hd-1));
            float y1c = __builtin_amdgcn_fmed3f(fl1.y, 0.f, (float)(Hd-1));
            float wx0z = (x0c == fl0.x) ? w0.x : 0.f;   // in-bounds <=> clamp identity
            float wx1z = (x1c == fl1.x) ? w1.x : 0.f;
            float wy0z = (y0c == fl0.y) ? w0.y : 0.f;
            float wy1z = (y1c == fl1.y) ? w1.y : 0.f;
            vf2 wx = (vf2){wx0z, wx1z};
            vf2 row0 = wx * (vf2){wy0z, wy0z};  // w00, w10
            vf2 row1 = wx * (vf2){wy1z, wy1z};  // w01, w11
            int x0 = (int)x0c, x1 = (int)x1c, y0 = (int)y0c, y1 = (int)y1c;
            int r0 = y0 << 14, r1 = y1 << 14;   // row byte offsets
            int c0 = (x0 << 7) + g16;           // col byte offset + group
            int c1 = (x1 << 7) + g16;

            // wave-uniform base (SGPR) + 32-bit zext voffset
            const char* vb = (const char*)srcT + (size_t)v * ((size_t)Cc * HWSZ * 4);
            vf4 t00 = *(const vf4*)(vb + (unsigned)(r0 + c0));
            vf4 t10 = *(const vf4*)(vb + (unsigned)(r0 + c1));
            vf4 t01 = *(const vf4*)(vb + (unsigned)(r1 + c0));
            vf4 t11 = *(const vf4*)(vb + (unsigned)(r1 + c1));
            a4 += t00 * (vf4){row0.x, row0.x, row0.x, row0.x};
            a4 += t10 * (vf4){row0.y, row0.y, row0.y, row0.y};
            a4 += t01 * (vf4){row1.x, row1.x, row1.x, row1.x};
            a4 += t11 * (vf4){row1.y, row1.y, row1.y, row1.y};
        }
        float s = r4.x*a4.x + r4.y*a4.y + r4.z*a4.z + r4.w*a4.w;
        vo[(size_t)dd * HWSZ] = s * (1.f / 16.f);   // /(C/G)=4 then /(V-1)=4
    }
}

// ---------------- kernel 3 (fallback, no workspace): original layout ------
__global__ __launch_bounds__(256) void k_volume_fb(const float* __restrict__ featsrc,
                                                   const int* __restrict__ idx,
                                                   const float* __restrict__ dvals,
                                                   const float* __restrict__ proj,
                                                   float* __restrict__ volume) {
    __shared__ float P[48];
    __shared__ int sidx[5];
    int t = threadIdx.x;
    if (t < 48) P[t] = proj[t];
    if (t < 5)  sidx[t] = idx[t];
    __syncthreads();

    int tid = blockIdx.x * 256 + t;
    int w = tid & (Wd - 1);
    int h = (tid >> 7) & (Hd - 1);
    int pix = tid & (HWSZ - 1);
    float fx = (float)w, fy = (float)h;
    float dep = dvals[tid];

    float acc[Cc];
#pragma unroll
    for (int c = 0; c < Cc; ++c) acc[c] = 0.f;

#pragma unroll 1
    for (int v = 0; v < 4; ++v) {
        const float* p = &P[v * 12];
        float sx = (p[0]*fx + p[1]*fy + p[2])  * dep + p[3];
        float sy = (p[4]*fx + p[5]*fy + p[6])  * dep + p[7];
        float sz = (p[8]*fx + p[9]*fy + p[10]) * dep + p[11];
        sz = (fabsf(sz) < 1e-6f) ? 1e-6f : sz;
        float gx = sx / sz, gy = sy / sz;

        float x0f = floorf(gx), y0f = floorf(gy);
        float wx1 = gx - x0f, wx0 = 1.f - wx1;
        float wy1 = gy - y0f, wy0 = 1.f - wy1;
        float x1f = x0f + 1.f, y1f = y0f + 1.f;
        bool xi0 = (x0f >= 0.f) && (x0f <= (float)(Wd-1));
        bool xi1 = (x1f >= 0.f) && (x1f <= (float)(Wd-1));
        bool yi0 = (y0f >= 0.f) && (y0f <= (float)(Hd-1));
        bool yi1 = (y1f >= 0.f) && (y1f <= (float)(Hd-1));
        float w00 = wx0*wy0 * ((xi0 && yi0) ? 1.f : 0.f);
        float w10 = wx1*wy0 * ((xi1 && yi0) ? 1.f : 0.f);
        float w01 = wx0*wy1 * ((xi0 && yi1) ? 1.f : 0.f);
        float w11 = wx1*wy1 * ((xi1 && yi1) ? 1.f : 0.f);
        int x0 = (int)fminf(fmaxf(x0f, 0.f), (float)(Wd-1));
        int x1 = (int)fminf(fmaxf(x1f, 0.f), (float)(Wd-1));
        int y0 = (int)fminf(fmaxf(y0f, 0.f), (float)(Hd-1));
        int y1 = (int)fminf(fmaxf(y1f, 0.f), (float)(Hd-1));

        int vv = sidx[v + 1];
        const float* base = featsrc + (size_t)vv * Cc * HWSZ;
        int o00 = y0*Wd + x0, o10 = y0*Wd + x1, o01 = y1*Wd + x0, o11 = y1*Wd + x1;
#pragma unroll
        for (int c = 0; c < Cc; ++c) {
            const float* bc = base + (size_t)c * HWSZ;
            acc[c] += bc[o00]*w00 + bc[o10]*w10 + bc[o01]*w01 + bc[o11]*w11;
        }
    }

    float ref[Cc];
    int v0 = sidx[0];
    const float* rb = featsrc + (size_t)v0 * Cc * HWSZ + pix;
#pragma unroll
    for (int c = 0; c < Cc; ++c) ref[c] = rb[(size_t)c * HWSZ];
#pragma unroll
    for (int g = 0; g < Gg; ++g) {
        float s = ref[g*4+0]*acc[g*4+0] + ref[g*4+1]*acc[g*4+1]
                + ref[g*4+2]*acc[g*4+2] + ref[g*4+3]*acc[g*4+3];
        volume[(size_t)g * DHW + tid] = s * (1.f / 16.f);
    }
}

// ---------------- kernel 4: 3D conv (G->1, 3x3x3, SAME), Wtile=4 ----------
__global__ __launch_bounds__(256) void k_conv(const float* __restrict__ volume,
                                              const float* __restrict__ cw,
                                              const float* __restrict__ cb,
                                              float* __restrict__ dp) {
    __shared__ float Wk[216];
    __shared__ float bias;
    int t = threadIdx.x;
    if (t < 216) Wk[t] = cw[t];
    if (t == 0) bias = cb[0];
    __syncthreads();

    int T  = blockIdx.x * 256 + t;
    int wg = T & 31;
    int w0 = wg << 2;
    int h  = (T >> 5) & 127;
    int d  = T >> 12;
    bool left  = (w0 == 0);
    bool right = (w0 == 124);
    int c0 = left  ? 0   : w0 - 1;
    int c1 = right ? 124 : w0 + 1;

    float acc0 = 0.f, acc1 = 0.f, acc2 = 0.f, acc3 = 0.f;

#pragma unroll 1
    for (int g = 0; g < Gg; ++g) {
        float wt[27];
#pragma unroll
        for (int j = 0; j < 27; ++j) wt[j] = Wk[g * 27 + j];
        const float* vg = volume + (size_t)g * DHW;
#pragma unroll
        for (int pz = 0; pz < 3; ++pz) {
            int dd = d - 1 + pz;
            if (dd < 0 || dd >= Dd) continue;
            const float* vp = vg + (size_t)dd * HWSZ;
#pragma unroll
            for (int dy = 0; dy < 3; ++dy) {
                int hh = h - 1 + dy;
                if (hh < 0 || hh >= Hd) continue;
                const float* vr = vp + hh * Wd;
                float4a L0 = *(const float4a*)(vr + c0);
                float4a L1 = *(const float4a*)(vr + c1);
                float n0 = left  ? 0.f  : L0.x;
                float n1 = left  ? L0.x : L0.y;
                float n2 = left  ? L0.y : L0.z;
                float n3 = left  ? L0.z : L0.w;
                float n4 = right ? L1.w : L1.z;
                float n5 = right ? 0.f  : L1.w;
                float wa = wt[pz*9 + dy*3 + 0];
                float wb = wt[pz*9 + dy*3 + 1];
                float wc = wt[pz*9 + dy*3 + 2];
                acc0 += n0*wa + n1*wb + n2*wc;
                acc1 += n1*wa + n2*wb + n3*wc;
                acc2 += n2*wa + n3*wb + n4*wc;
                acc3 += n3*wa + n4*wb + n5*wc;
            }
        }
    }
    size_t o = (size_t)d * HWSZ + (size_t)h * Wd + w0;
    dp[o + 0] = acc0 + bias;
    dp[o + 1] = acc1 + bias;
    dp[o + 2] = acc2 + bias;
    dp[o + 3] = acc3 + bias;
}

// ---------------- kernel 5: softmax over D + expected depth ---------------
__global__ __launch_bounds__(256) void k_depth(const float* __restrict__ dp,
                                               const float* __restrict__ dvals,
                                               float* __restrict__ out) {
    int pix = blockIdx.x * 256 + threadIdx.x;
    float p[Dd];
#pragma unroll
    for (int d = 0; d < Dd; ++d) p[d] = dp[(size_t)d * HWSZ + pix];
    float m = p[0];
#pragma unroll
    for (int d = 1; d < Dd; ++d) m = fmaxf(m, p[d]);
    float se = 0.f, acc = 0.f;
#pragma unroll
    for (int d = 0; d < Dd; ++d) {
        float e = __expf(p[d] - m);
        se += e;
        acc += e * dvals[(size_t)d * HWSZ + pix];
    }
    out[pix] = acc / se;
}

extern "C" void kernel_launch(void* const* d_in, const int* in_sizes, int n_in,
                              void* d_out, int out_size, void* d_ws, size_t ws_size,
                              hipStream_t stream) {
    const float* feats = (const float*)d_in[0];
    const float* am    = (const float*)d_in[1];
    const float* ainv  = (const float*)d_in[2];
    const float* dvals = (const float*)d_in[3];
    const float* cw    = (const float*)d_in[4];
    const float* cb    = (const float*)d_in[5];
    const int*   idx   = (const int*)d_in[6];

    float* out    = (float*)d_out;
    float* volume = out;                         // G*D*H*W
    float* depth  = out + (size_t)Gg * DHW;      // H*W

    float* ws   = (float*)d_ws;
    float* proj = ws;                            // 48 floats (pad to 256)
    float* dp   = ws + 256;                      // DHW floats
    float* refT = ws + 256 + DHW;                // Cc*HWSZ floats
    float* srcT = refT + (size_t)Cc * HWSZ;      // 4*Cc*HWSZ floats
    size_t need = (256 + (size_t)DHW + (size_t)Cc * HWSZ * 5) * sizeof(float);
    bool tr = ws_size >= need;

    k_proj<<<dim3(1), dim3(64), 0, stream>>>(am, ainv, idx, proj);
    if (tr) {
        k_transpose<<<dim3((Vv * HWSZ) / 64), dim3(256), 0, stream>>>(feats, idx, refT, srcT);
        k_volume8<<<dim3((HWSZ * Gg * NCHUNK) / 256), dim3(256), 0, stream>>>(srcT, refT, dvals, proj, volume);
    } else {
        k_volume_fb<<<dim3(DHW / 256), dim3(256), 0, stream>>>(feats, idx, dvals, proj, volume);
    }
    k_conv<<<dim3(DHW / 1024), dim3(256), 0, stream>>>(volume, cw, cb, dp);
    k_depth<<<dim3(HWSZ / 256), dim3(256), 0, stream>>>(dp, dvals, depth);
}

// Round 6
// 95.739 us; speedup vs baseline: 1.2686x; 1.0093x over previous
//
#include <hip/hip_runtime.h>

#define HWSZ 16384      // H*W
#define Wd 128
#define Hd 128
#define Dd 48
#define Cc 32
#define Gg 8
#define Vv 5
#define DHW (Dd*HWSZ)   // 786432
#define NCHUNK 4
#define DCH (Dd/NCHUNK) // 12 depths per thread

typedef float float4a __attribute__((ext_vector_type(4), aligned(4)));
typedef float vf2 __attribute__((ext_vector_type(2)));
typedef float vf4 __attribute__((ext_vector_type(4)));

// ---------------- kernel 1: proj matrices (4 views x 3x4) ----------------
__global__ void k_proj(const float* __restrict__ am, const float* __restrict__ ainv,
                       const int* __restrict__ idx, float* __restrict__ proj) {
    int t = threadIdx.x;
    if (t >= 4) return;
    int i0 = idx[0];
    int ii = idx[t + 1];
    const float* A  = am   + ii * 16;
    const float* Mi = ainv + i0 * 16;
    for (int r = 0; r < 3; ++r)
        for (int c = 0; c < 4; ++c) {
            float s = 0.f;
            for (int k = 0; k < 4; ++k) s += A[r*4+k] * Mi[k*4+c];
            proj[t*12 + r*4 + c] = s;
        }
}

// ---------------- kernel 2: transpose (C,H,W) -> (H,W,C), LDS-tiled -------
__global__ __launch_bounds__(256) void k_transpose(const float* __restrict__ feats,
                                                   const int* __restrict__ idx,
                                                   float* __restrict__ refT,
                                                   float* __restrict__ srcT) {
    __shared__ float tile[Cc][64 + 1];
    int t = threadIdx.x;
    int slot = blockIdx.x >> 8;
    int px0  = (blockIdx.x & 255) << 6;
    int v = idx[slot];
    const float* s = feats + (size_t)v * Cc * HWSZ + px0;
    int cr = t >> 6;
    int pr = t & 63;
#pragma unroll
    for (int k = 0; k < 8; ++k) {
        int c = cr + k * 4;
        tile[c][pr] = s[(size_t)c * HWSZ + pr];
    }
    __syncthreads();
    float* dbase = (slot == 0) ? (refT + ((size_t)px0 << 5))
                               : (srcT + (size_t)(slot - 1) * Cc * HWSZ + ((size_t)px0 << 5));
    int cw = t & 31;
    int pw = t >> 5;
#pragma unroll
    for (int k = 0; k < 8; ++k) {
        int p = pw + k * 8;
        dbase[((size_t)p << 5) + cw] = tile[cw][p];
    }
}

// ---------------- kernel 3 (TR path): warp + group correlation ------------
// 8 lanes per pixel (one per group); lane-private setup (R4 micro-opts kept:
// packed f32 math, SGPR-base + 32-bit voffset, fmed3 clamps, uniform depth
// s_loads). R5 restructure for L1 depth-reuse: VIEW LOOP OUTERMOST, 12
// consecutive depths innermost (fully unrolled, static acc[12] indexing),
// blocks cover 8x4 2D pixel patches. Near-identity warp => a (pixel,view)'s
// 4 corner lines are ~constant across all depths -> fetched once from L2,
// then L1-hit 11x. Accumulation order per acc element unchanged (v
// ascending, corners in 00,10,01,11 order).
__global__ __launch_bounds__(256, 4) void k_volume8(const float* __restrict__ srcT,
                                                    const float* __restrict__ refT,
                                                    const float* __restrict__ dvals,
                                                    const float* __restrict__ proj,
                                                    float* __restrict__ volume) {
    int t = threadIdx.x;
    int g = t & 7;
    int p = t >> 3;                     // 0..31 within patch
    int px = p & 7, py = p >> 3;        // 8x4 patch
    int b = blockIdx.x;
    int chunk = b >> 9;                 // 0..NCHUNK-1
    int tb = b & 511;
    int tile_x = tb & 15;               // 16 tiles of 8 px
    int tile_y = tb >> 4;               // 32 tiles of 4 px
    int w = (tile_x << 3) + px;
    int h = (tile_y << 2) + py;
    int pix = (h << 7) + w;
    float fx = (float)w, fy = (float)h;

    // wave-uniform depth values for this chunk (SGPR-resident)
    float dep_s[DCH];
#pragma unroll
    for (int dd = 0; dd < DCH; ++dd)
        dep_s[dd] = dvals[(size_t)(chunk * DCH + dd) * HWSZ];

    vf4 r4 = *(const vf4*)(refT + ((size_t)pix << 5) + (g << 2));
    int g16 = g << 4;                   // group byte offset inside a pixel line

    vf4 acc[DCH];
#pragma unroll
    for (int dd = 0; dd < DCH; ++dd) acc[dd] = (vf4){0.f, 0.f, 0.f, 0.f};

#pragma unroll 1
    for (int v = 0; v < 4; ++v) {
        const float* pj = proj + v * 12;
        vf2 rxy = (vf2){pj[0]*fx + pj[1]*fy + pj[2], pj[4]*fx + pj[5]*fy + pj[6]};
        vf2 txy = (vf2){pj[3], pj[7]};
        float rz = pj[8]*fx + pj[9]*fy + pj[10];
        float tz = pj[11];
        const char* vb = (const char*)srcT + (size_t)v * ((size_t)Cc * HWSZ * 4);

#pragma unroll
        for (int dd = 0; dd < DCH; ++dd) {
            float dep = dep_s[dd];
            vf2 sxy = rxy * (vf2){dep, dep} + txy;
            float sz = rz * dep + tz;
            sz = (fabsf(sz) < 1e-6f) ? 1e-6f : sz;
            float rzi = __builtin_amdgcn_rcpf(sz);
            vf2 gxy = sxy * (vf2){rzi, rzi};

            vf2 fl0 = (vf2){floorf(gxy.x), floorf(gxy.y)};
            vf2 w1 = gxy - fl0;                 // wx1, wy1
            vf2 w0 = (vf2){1.f, 1.f} - w1;      // wx0, wy0
            vf2 fl1 = fl0 + (vf2){1.f, 1.f};
            float x0c = __builtin_amdgcn_fmed3f(fl0.x, 0.f, (float)(Wd-1));
            float x1c = __builtin_amdgcn_fmed3f(fl1.x, 0.f, (float)(Wd-1));
            float y0c = __builtin_amdgcn_fmed3f(fl0.y, 0.f, (float)(Hd-1));
            float y1c = __builtin_amdgcn_fmed3f(fl1.y, 0.f, (float)(Hd-1));
            float wx0z = (x0c == fl0.x) ? w0.x : 0.f;
            float wx1z = (x1c == fl1.x) ? w1.x : 0.f;
            float wy0z = (y0c == fl0.y) ? w0.y : 0.f;
            float wy1z = (y1c == fl1.y) ? w1.y : 0.f;
            vf2 wx = (vf2){wx0z, wx1z};
            vf2 row0 = wx * (vf2){wy0z, wy0z};  // w00, w10
            vf2 row1 = wx * (vf2){wy1z, wy1z};  // w01, w11
            int x0 = (int)x0c, x1 = (int)x1c, y0 = (int)y0c, y1 = (int)y1c;
            int r0 = y0 << 14, r1 = y1 << 14;
            int c0 = (x0 << 7) + g16;
            int c1 = (x1 << 7) + g16;

            vf4 t00 = *(const vf4*)(vb + (unsigned)(r0 + c0));
            vf4 t10 = *(const vf4*)(vb + (unsigned)(r0 + c1));
            vf4 t01 = *(const vf4*)(vb + (unsigned)(r1 + c0));
            vf4 t11 = *(const vf4*)(vb + (unsigned)(r1 + c1));
            vf4 a = acc[dd];
            a += t00 * (vf4){row0.x, row0.x, row0.x, row0.x};
            a += t10 * (vf4){row0.y, row0.y, row0.y, row0.y};
            a += t01 * (vf4){row1.x, row1.x, row1.x, row1.x};
            a += t11 * (vf4){row1.y, row1.y, row1.y, row1.y};
            acc[dd] = a;
        }
    }

    float* vo = volume + (size_t)g * DHW + (size_t)chunk * DCH * HWSZ + pix;
#pragma unroll
    for (int dd = 0; dd < DCH; ++dd) {
        vf4 a = acc[dd];
        float s = r4.x*a.x + r4.y*a.y + r4.z*a.z + r4.w*a.w;
        vo[(size_t)dd * HWSZ] = s * (1.f / 16.f);   // /(C/G)=4 then /(V-1)=4
    }
}

// ---------------- kernel 3 (fallback, no workspace): original layout ------
__global__ __launch_bounds__(256) void k_volume_fb(const float* __restrict__ featsrc,
                                                   const int* __restrict__ idx,
                                                   const float* __restrict__ dvals,
                                                   const float* __restrict__ proj,
                                                   float* __restrict__ volume) {
    __shared__ float P[48];
    __shared__ int sidx[5];
    int t = threadIdx.x;
    if (t < 48) P[t] = proj[t];
    if (t < 5)  sidx[t] = idx[t];
    __syncthreads();

    int tid = blockIdx.x * 256 + t;
    int w = tid & (Wd - 1);
    int h = (tid >> 7) & (Hd - 1);
    int pix = tid & (HWSZ - 1);
    float fx = (float)w, fy = (float)h;
    float dep = dvals[tid];

    float acc[Cc];
#pragma unroll
    for (int c = 0; c < Cc; ++c) acc[c] = 0.f;

#pragma unroll 1
    for (int v = 0; v < 4; ++v) {
        const float* p = &P[v * 12];
        float sx = (p[0]*fx + p[1]*fy + p[2])  * dep + p[3];
        float sy = (p[4]*fx + p[5]*fy + p[6])  * dep + p[7];
        float sz = (p[8]*fx + p[9]*fy + p[10]) * dep + p[11];
        sz = (fabsf(sz) < 1e-6f) ? 1e-6f : sz;
        float gx = sx / sz, gy = sy / sz;

        float x0f = floorf(gx), y0f = floorf(gy);
        float wx1 = gx - x0f, wx0 = 1.f - wx1;
        float wy1 = gy - y0f, wy0 = 1.f - wy1;
        float x1f = x0f + 1.f, y1f = y0f + 1.f;
        bool xi0 = (x0f >= 0.f) && (x0f <= (float)(Wd-1));
        bool xi1 = (x1f >= 0.f) && (x1f <= (float)(Wd-1));
        bool yi0 = (y0f >= 0.f) && (y0f <= (float)(Hd-1));
        bool yi1 = (y1f >= 0.f) && (y1f <= (float)(Hd-1));
        float w00 = wx0*wy0 * ((xi0 && yi0) ? 1.f : 0.f);
        float w10 = wx1*wy0 * ((xi1 && yi0) ? 1.f : 0.f);
        float w01 = wx0*wy1 * ((xi0 && yi1) ? 1.f : 0.f);
        float w11 = wx1*wy1 * ((xi1 && yi1) ? 1.f : 0.f);
        int x0 = (int)fminf(fmaxf(x0f, 0.f), (float)(Wd-1));
        int x1 = (int)fminf(fmaxf(x1f, 0.f), (float)(Wd-1));
        int y0 = (int)fminf(fmaxf(y0f, 0.f), (float)(Hd-1));
        int y1 = (int)fminf(fmaxf(y1f, 0.f), (float)(Hd-1));

        int vv = sidx[v + 1];
        const float* base = featsrc + (size_t)vv * Cc * HWSZ;
        int o00 = y0*Wd + x0, o10 = y0*Wd + x1, o01 = y1*Wd + x0, o11 = y1*Wd + x1;
#pragma unroll
        for (int c = 0; c < Cc; ++c) {
            const float* bc = base + (size_t)c * HWSZ;
            acc[c] += bc[o00]*w00 + bc[o10]*w10 + bc[o01]*w01 + bc[o11]*w11;
        }
    }

    float ref[Cc];
    int v0 = sidx[0];
    const float* rb = featsrc + (size_t)v0 * Cc * HWSZ + pix;
#pragma unroll
    for (int c = 0; c < Cc; ++c) ref[c] = rb[(size_t)c * HWSZ];
#pragma unroll
    for (int g = 0; g < Gg; ++g) {
        float s = ref[g*4+0]*acc[g*4+0] + ref[g*4+1]*acc[g*4+1]
                + ref[g*4+2]*acc[g*4+2] + ref[g*4+3]*acc[g*4+3];
        volume[(size_t)g * DHW + tid] = s * (1.f / 16.f);
    }
}

// ---------------- kernel 4: 3D conv (G->1, 3x3x3, SAME), Wtile=4 ----------
__global__ __launch_bounds__(256) void k_conv(const float* __restrict__ volume,
                                              const float* __restrict__ cw,
                                              const float* __restrict__ cb,
                                              float* __restrict__ dp) {
    __shared__ float Wk[216];
    __shared__ float bias;
    int t = threadIdx.x;
    if (t < 216) Wk[t] = cw[t];
    if (t == 0) bias = cb[0];
    __syncthreads();

    int T  = blockIdx.x * 256 + t;
    int wg = T & 31;
    int w0 = wg << 2;
    int h  = (T >> 5) & 127;
    int d  = T >> 12;
    bool left  = (w0 == 0);
    bool right = (w0 == 124);
    int c0 = left  ? 0   : w0 - 1;
    int c1 = right ? 124 : w0 + 1;

    float acc0 = 0.f, acc1 = 0.f, acc2 = 0.f, acc3 = 0.f;

#pragma unroll 1
    for (int g = 0; g < Gg; ++g) {
        float wt[27];
#pragma unroll
        for (int j = 0; j < 27; ++j) wt[j] = Wk[g * 27 + j];
        const float* vg = volume + (size_t)g * DHW;
#pragma unroll
        for (int pz = 0; pz < 3; ++pz) {
            int dd = d - 1 + pz;
            if (dd < 0 || dd >= Dd) continue;
            const float* vp = vg + (size_t)dd * HWSZ;
#pragma unroll
            for (int dy = 0; dy < 3; ++dy) {
                int hh = h - 1 + dy;
                if (hh < 0 || hh >= Hd) continue;
                const float* vr = vp + hh * Wd;
                float4a L0 = *(const float4a*)(vr + c0);
                float4a L1 = *(const float4a*)(vr + c1);
                float n0 = left  ? 0.f  : L0.x;
                float n1 = left  ? L0.x : L0.y;
                float n2 = left  ? L0.y : L0.z;
                float n3 = left  ? L0.z : L0.w;
                float n4 = right ? L1.w : L1.z;
                float n5 = right ? 0.f  : L1.w;
                float wa = wt[pz*9 + dy*3 + 0];
                float wb = wt[pz*9 + dy*3 + 1];
                float wc = wt[pz*9 + dy*3 + 2];
                acc0 += n0*wa + n1*wb + n2*wc;
                acc1 += n1*wa + n2*wb + n3*wc;
                acc2 += n2*wa + n3*wb + n4*wc;
                acc3 += n3*wa + n4*wb + n5*wc;
            }
        }
    }
    size_t o = (size_t)d * HWSZ + (size_t)h * Wd + w0;
    dp[o + 0] = acc0 + bias;
    dp[o + 1] = acc1 + bias;
    dp[o + 2] = acc2 + bias;
    dp[o + 3] = acc3 + bias;
}

// ---------------- kernel 5: softmax over D + expected depth ---------------
__global__ __launch_bounds__(256) void k_depth(const float* __restrict__ dp,
                                               const float* __restrict__ dvals,
                                               float* __restrict__ out) {
    int pix = blockIdx.x * 256 + threadIdx.x;
    float p[Dd];
#pragma unroll
    for (int d = 0; d < Dd; ++d) p[d] = dp[(size_t)d * HWSZ + pix];
    float m = p[0];
#pragma unroll
    for (int d = 1; d < Dd; ++d) m = fmaxf(m, p[d]);
    float se = 0.f, acc = 0.f;
#pragma unroll
    for (int d = 0; d < Dd; ++d) {
        float e = __expf(p[d] - m);
        se += e;
        acc += e * dvals[(size_t)d * HWSZ + pix];
    }
    out[pix] = acc / se;
}

extern "C" void kernel_launch(void* const* d_in, const int* in_sizes, int n_in,
                              void* d_out, int out_size, void* d_ws, size_t ws_size,
                              hipStream_t stream) {
    const float* feats = (const float*)d_in[0];
    const float* am    = (const float*)d_in[1];
    const float* ainv  = (const float*)d_in[2];
    const float* dvals = (const float*)d_in[3];
    const float* cw    = (const float*)d_in[4];
    const float* cb    = (const float*)d_in[5];
    const int*   idx   = (const int*)d_in[6];

    float* out    = (float*)d_out;
    float* volume = out;                         // G*D*H*W
    float* depth  = out + (size_t)Gg * DHW;      // H*W

    float* ws   = (float*)d_ws;
    float* proj = ws;                            // 48 floats (pad to 256)
    float* dp   = ws + 256;                      // DHW floats
    float* refT = ws + 256 + DHW;                // Cc*HWSZ floats
    float* srcT = refT + (size_t)Cc * HWSZ;      // 4*Cc*HWSZ floats
    size_t need = (256 + (size_t)DHW + (size_t)Cc * HWSZ * 5) * sizeof(float);
    bool tr = ws_size >= need;

    k_proj<<<dim3(1), dim3(64), 0, stream>>>(am, ainv, idx, proj);
    if (tr) {
        k_transpose<<<dim3((Vv * HWSZ) / 64), dim3(256), 0, stream>>>(feats, idx, refT, srcT);
        k_volume8<<<dim3((HWSZ / 32) * NCHUNK), dim3(256), 0, stream>>>(srcT, refT, dvals, proj, volume);
    } else {
        k_volume_fb<<<dim3(DHW / 256), dim3(256), 0, stream>>>(feats, idx, dvals, proj, volume);
    }
    k_conv<<<dim3(DHW / 1024), dim3(256), 0, stream>>>(volume, cw, cb, dp);
    k_depth<<<dim3(HWSZ / 256), dim3(256), 0, stream>>>(dp, dvals, depth);
}